// Round 23
// baseline (131.790 us; speedup 1.0000x reference)
//
#include <hip/hip_runtime.h>
#include <hip/hip_bf16.h>

#define NN 4096
#define INS 512
#define HIDW 512
#define MIDW 64
#define OUTW 128
#define CAP 384   // per-row packed nonzero capacity (mean ~205)
#define SEG 96    // per-512-col-strip slot capacity
#define BN_EPS 1e-5f
#define NSTRIP 8                   // 512-col strips per row
#define NPAIR (NSTRIP / 2)         // 4 strip-pairs per row
#define SLOTCAP (NSTRIP * SEG)     // 768 slotted entries per row
#define CS_BLOCKS 256              // colsum blocks (16 rows each, 4/wave)
#define CS_ROWS 16

// ---------------------------------------------------------------------------
// device: thin GEMM block  C[32 rows x 64] = (A(+abias)) @ (B (*s1 rows))
// Register-batched staging (all 24 loads in flight before LDS stores).
// BSCALE: B row k scaled by s1(k)=bg[k]*rsqrt(bv[k]+eps) at staging time.
// ---------------------------------------------------------------------------
template <bool BSCALE>
__device__ __forceinline__ void thin_block(
    const float* __restrict__ A, const float* __restrict__ B,
    const float* __restrict__ abias,
    const float* __restrict__ bg, const float* __restrict__ bv,
    float* __restrict__ C, int K, int bb,
    float (*As)[36], float (*Bs)[64])
{
    const int t = threadIdx.x;
    const int bm = bb * 32;
    const int c2 = t & 31, rg = t >> 5;

    float acc[4][2] = {};
    for (int k0 = 0; k0 < K; k0 += 64) {
        float va[8];
        #pragma unroll
        for (int l = 0; l < 8; ++l) {
            int e = t + l * 256;
            va[l] = A[(size_t)(bm + (e >> 6)) * K + k0 + (e & 63)];
        }
        float vb[16];
        #pragma unroll
        for (int l = 0; l < 16; ++l) {
            int e = t + l * 256;
            vb[l] = B[(size_t)(k0 + (e >> 6)) * 64 + (e & 63)];
        }
        #pragma unroll
        for (int l = 0; l < 8; ++l) {
            int e = t + l * 256;
            float v = va[l];
            if (abias) v += abias[k0 + (e & 63)];
            As[e & 63][e >> 6] = v;
        }
        #pragma unroll
        for (int l = 0; l < 16; ++l) {
            int e = t + l * 256;
            float v = vb[l];
            if (BSCALE) {
                int k = k0 + (e >> 6);
                v *= bg[k] * rsqrtf(bv[k] + BN_EPS);
            }
            Bs[e >> 6][e & 63] = v;
        }
        __syncthreads();
        #pragma unroll
        for (int k = 0; k < 64; ++k) {
            float4 a4 = *reinterpret_cast<const float4*>(&As[k][rg * 4]);
            float2 b2 = *reinterpret_cast<const float2*>(&Bs[k][2 * c2]);
            acc[0][0] = fmaf(a4.x, b2.x, acc[0][0]);
            acc[0][1] = fmaf(a4.x, b2.y, acc[0][1]);
            acc[1][0] = fmaf(a4.y, b2.x, acc[1][0]);
            acc[1][1] = fmaf(a4.y, b2.y, acc[1][1]);
            acc[2][0] = fmaf(a4.z, b2.x, acc[2][0]);
            acc[2][1] = fmaf(a4.z, b2.y, acc[2][1]);
            acc[3][0] = fmaf(a4.w, b2.x, acc[3][0]);
            acc[3][1] = fmaf(a4.w, b2.y, acc[3][1]);
        }
        __syncthreads();
    }
    #pragma unroll
    for (int u = 0; u < 4; ++u) {
        int r = bm + rg * 4 + u;
        *reinterpret_cast<float2*>(&C[(size_t)r * 64 + 2 * c2]) =
            make_float2(acc[u][0], acc[u][1]);
    }
}

// ---------------------------------------------------------------------------
// K1: block 0 = prep (c1, s2g, t2g); blocks 1..16 = W2 = gc1 @ (s1⊙lin2)
// (s1 folded into B staging — no Wp dependency); blocks 17.. = adj count.
// ---------------------------------------------------------------------------
__global__ __launch_bounds__(256) void k_count_prep(
    const float* __restrict__ adj,
    int* __restrict__ cslot, int* __restrict__ cnt, int* __restrict__ dflag,
    const float* __restrict__ gc1_w,
    const float* __restrict__ lin2_w, const float* __restrict__ lin2_b,
    const float* __restrict__ bn1_g, const float* __restrict__ bn1_b,
    const float* __restrict__ bn1_m, const float* __restrict__ bn1_v,
    const float* __restrict__ bn2_g, const float* __restrict__ bn2_b,
    const float* __restrict__ bn2_m, const float* __restrict__ bn2_v,
    float* __restrict__ W2, float* __restrict__ c1,
    float* __restrict__ s2g, float* __restrict__ t2g)
{
    const int t = threadIdx.x;
    if (blockIdx.x == 0) {
        __shared__ float t1s[HIDW];
        for (int h = t; h < HIDW; h += 256) {
            float s1 = bn1_g[h] * rsqrtf(bn1_v[h] + BN_EPS);
            t1s[h] = bn1_b[h] - bn1_m[h] * s1;
        }
        __syncthreads();
        if (t < MIDW) {
            float acc = lin2_b[t];
            for (int h = 0; h < HIDW; ++h)
                acc = fmaf(t1s[h], lin2_w[(size_t)h * MIDW + t], acc);
            c1[t] = acc;
        } else if (t >= 64 && t < 64 + OUTW) {
            int j = t - 64;
            float s2 = bn2_g[j] * rsqrtf(bn2_v[j] + BN_EPS);
            s2g[j] = s2;
            t2g[j] = bn2_b[j] - bn2_m[j] * s2;
        }
        return;
    }
    if (blockIdx.x <= INS / 32) {
        __shared__ float As[64][36];
        __shared__ float Bs[64][64];
        thin_block<true>(gc1_w, lin2_w, nullptr, bn1_g, bn1_v, W2, HIDW,
                         blockIdx.x - 1, As, Bs);
        return;
    }
    const int wave = t >> 6, lane = t & 63;
    const int gw = (blockIdx.x - 1 - INS / 32) * 4 + wave;
    const int i = gw >> 3, s = gw & 7;
    const int colbase = s * 512;
    const float* __restrict__ base = adj + (size_t)i * NN + colbase + 4 * lane;
    float4 a4a = *reinterpret_cast<const float4*>(base);
    float4 a4b = *reinterpret_cast<const float4*>(base + 256);
    const float av[8] = {a4a.x, a4a.y, a4a.z, a4a.w,
                         a4b.x, a4b.y, a4b.z, a4b.w};
    int* __restrict__ slot = cslot + (size_t)i * SLOTCAP + s * SEG;
    const unsigned long long lt = (1ULL << lane) - 1ULL;
    int run = 0;
    #pragma unroll
    for (int c = 0; c < 8; ++c) {
        int col = colbase + ((c < 4) ? (4 * lane + c) : (256 + 4 * lane + c - 4));
        bool diag = (col == i);
        bool act = (av[c] != 0.f) || diag;
        if (diag) dflag[i] = (av[c] != 0.f) ? 1 : 0;
        unsigned long long m = __ballot(act);
        if (act) {
            int pos = run + __popcll(m & lt);
            if (pos < SEG) slot[pos] = col;
        }
        run += __popcll(m);
    }
    if (lane == 0) cnt[gw] = (run < SEG) ? run : SEG;
}

// ---------------------------------------------------------------------------
// K2: blocks 0..127 = Graw = (pe + pe_b) @ W2 ; blocks 128.. = gather-fill
// (strip-pairs).
// ---------------------------------------------------------------------------
__global__ __launch_bounds__(256) void k_fill_g(
    const float* __restrict__ xdeg, const float* __restrict__ ydeg,
    const int* __restrict__ cslot, const int* __restrict__ cnt,
    const int* __restrict__ dflag,
    const float* __restrict__ w1, const float* __restrict__ b1,
    const float* __restrict__ w2, const float* __restrict__ b2,
    float* __restrict__ a_vals, int* __restrict__ a_cols,
    float* __restrict__ rs_part,
    const float* __restrict__ pe_w, const float* __restrict__ pe_b,
    const float* __restrict__ W2, float* __restrict__ G)
{
    __shared__ float As[64][36];
    __shared__ float Bs[64][64];
    if (blockIdx.x < NN / 32) {
        thin_block<false>(pe_w, W2, pe_b, nullptr, nullptr, G, INS,
                          blockIdx.x, As, Bs);
        return;
    }
    __shared__ float shb[16], sw1x[16], sw1y[16], sw2[32], sb2[2];
    const int t = threadIdx.x;
    const int wave = t >> 6, lane = t & 63;
    if (t < 16) {
        shb[t]  = b1[t] + w1[t];
        sw1x[t] = w1[16 + t];
        sw1y[t] = w1[32 + t];
    }
    if (t < 32) sw2[t] = w2[t];
    if (t < 2)  sb2[t] = b2[t];
    __syncthreads();

    const int q = __builtin_amdgcn_readfirstlane(
        (blockIdx.x - NN / 32) * 4 + wave);
    const int i = q >> 2;
    const int sp = (q & 3) * 2;
    const int* __restrict__ cb = cnt + i * NSTRIP;
    int wb = 0;
    #pragma unroll
    for (int ss = 0; ss < NSTRIP; ++ss) if (ss < sp) wb += cb[ss];
    const int n0 = cb[sp];
    const int ntot = n0 + cb[sp + 1];
    const int hasde = dflag[i];
    const int* __restrict__ slot = cslot + (size_t)i * SLOTCAP + sp * SEG;
    const float* __restrict__ xrow = xdeg + (size_t)i * NN;
    const float* __restrict__ yrow = ydeg + (size_t)i * NN;
    float* __restrict__ gv = a_vals + (size_t)i * CAP;
    int*   __restrict__ gc = a_cols + (size_t)i * CAP;

    float local = 0.f;
    for (int p = lane; p < ntot; p += 64) {
        int col = (p < n0) ? slot[p] : slot[SEG + p - n0];
        float x = xrow[col];
        float y = yrow[col];
        float l0 = sb2[0], l1 = sb2[1];
        #pragma unroll
        for (int w = 0; w < 16; ++w) {
            float hw = fmaf(x, sw1x[w], shb[w]);
            hw = fmaf(y, sw1y[w], hw);
            hw = fmaxf(hw, 0.f);
            l0 = fmaf(hw, sw2[2 * w],     l0);
            l1 = fmaf(hw, sw2[2 * w + 1], l1);
        }
        float v = 1.f / (1.f + __expf(l0 - l1));
        if (col == i) v = hasde ? (v + 1.f) : 1.f;
        int gp = wb + p;
        if (gp < CAP) { gc[gp] = col; gv[gp] = v; }
        local += v;
    }
    #pragma unroll
    for (int o = 32; o >= 1; o >>= 1)
        local += __shfl_down(local, o, 64);
    if (lane == 0) rs_part[q] = local;
}

// ---------------------------------------------------------------------------
// K3: wave-parallel colsum. 256 blocks x 16 rows (4 rows/wave);
// one float4/int4 load round per row; predicated LDS atomics.
// ---------------------------------------------------------------------------
__global__ __launch_bounds__(256) void k_colsum(
    const float* __restrict__ a_vals, const int* __restrict__ a_cols,
    const int* __restrict__ cnt, float* __restrict__ P)
{
    __shared__ float ls[NN];
    const int t = threadIdx.x;
    const int wave = t >> 6, lane = t & 63;
    const int b = blockIdx.x;
    for (int j = t; j < NN; j += 256) ls[j] = 0.f;
    __syncthreads();
    const int r0 = b * CS_ROWS;
    #pragma unroll
    for (int rr = 0; rr < 4; ++rr) {
        const int r = r0 + wave * 4 + rr;
        int n = 0;
        #pragma unroll
        for (int ss = 0; ss < NSTRIP; ++ss) n += cnt[r * NSTRIP + ss];
        n = (n < CAP) ? n : CAP;
        const float* __restrict__ vr = a_vals + (size_t)r * CAP;
        const int*   __restrict__ cr = a_cols + (size_t)r * CAP;
        for (int p0 = 4 * lane; p0 < n; p0 += 256) {
            float4 v4 = *reinterpret_cast<const float4*>(vr + p0);
            int4   c4 = *reinterpret_cast<const int4*>(cr + p0);
            if (p0 + 0 < n) atomicAdd(&ls[c4.x], v4.x);
            if (p0 + 1 < n) atomicAdd(&ls[c4.y], v4.y);
            if (p0 + 2 < n) atomicAdd(&ls[c4.z], v4.z);
            if (p0 + 3 < n) atomicAdd(&ls[c4.w], v4.w);
        }
    }
    __syncthreads();
    for (int j = t; j < NN; j += 256)
        P[(size_t)b * NN + j] = ls[j];
}

// ---------------------------------------------------------------------------
// K4: degree scale factors
// ---------------------------------------------------------------------------
__global__ __launch_bounds__(512) void k_scale(
    const float* __restrict__ rs_part, const float* __restrict__ P,
    float* __restrict__ d_row, float* __restrict__ d_col)
{
    int j = blockIdx.x * 512 + threadIdx.x;
    float r = 0.f;
    #pragma unroll
    for (int s = 0; s < NPAIR; ++s) r += rs_part[j * NPAIR + s];
    d_row[j] = (r > 0.f) ? 1.f / sqrtf(r) : 0.f;
    float c = 0.f;
    for (int b = 0; b < CS_BLOCKS; ++b)
        c += P[(size_t)b * NN + j];
    d_col[j] = (c > 0.f) ? 1.f / sqrtf(c) : 0.f;
}

// ---------------------------------------------------------------------------
// K5/K6: 64-wide SpMM, two waves per row, 2 rows/block.
// COLFOLD: stage sv = a * d_col[col] (consumes Graw directly).
// WITH_MID: writes mid+R. !WITH_MID: fused epilogue out = (S@gc3)*s2 + t2.
// ---------------------------------------------------------------------------
template <bool WITH_MID>
__global__ __launch_bounds__(256) void k_spmm(
    const float* __restrict__ a_vals, const int* __restrict__ a_cols,
    const int* __restrict__ cnt, const float* __restrict__ X,
    const float* __restrict__ d_row, const float* __restrict__ d_col,
    const float* __restrict__ c1,
    const float* __restrict__ gc3, const float* __restrict__ s2g,
    const float* __restrict__ t2g,
    float* __restrict__ O1, float* __restrict__ O2)
{
    __shared__ float sv[2][CAP];
    __shared__ int   scl[2][CAP];
    __shared__ float sacc[4][64];
    const int t = threadIdx.x;
    const int wave = t >> 6, lane = t & 63;
    const int rb = wave >> 1, h = wave & 1;
    const int i = blockIdx.x * 2 + rb;
    int n = 0;
    #pragma unroll
    for (int ss = 0; ss < NSTRIP; ++ss) n += cnt[i * NSTRIP + ss];
    n = (n < CAP) ? n : CAP;
    const int n16 = (n + 15) & ~15;
    const float* __restrict__ vrow = a_vals + (size_t)i * CAP;
    const int*   __restrict__ crow = a_cols + (size_t)i * CAP;

    for (int p = h * 64 + lane; p < n16; p += 128) {
        bool ok = p < n;
        int c = ok ? crow[p] : 0;
        float v = ok ? vrow[p] : 0.f;
        if (WITH_MID) v *= d_col[c];       // fold Dc into the edge weight
        sv[rb][p]  = v;
        scl[rb][p] = c;
    }
    __syncthreads();

    const int eh = lane >> 5;
    const int lc = lane & 31;
    const int Q  = n16 >> 1;
    const int Qh = Q >> 1;

    float a0 = 0.f, a1 = 0.f;
    for (int q = h * Qh; q < (h + 1) * Qh; q += 4) {
        #pragma unroll
        for (int j = 0; j < 4; ++j) {
            int p = 2 * (q + j) + eh;
            float v = sv[rb][p];
            int c = scl[rb][p];
            float2 x = *reinterpret_cast<const float2*>(X + (size_t)c * 64 + 2 * lc);
            a0 = fmaf(v, x.x, a0);
            a1 = fmaf(v, x.y, a1);
        }
    }
    a0 += __shfl_xor(a0, 32);
    a1 += __shfl_xor(a1, 32);
    if (lane < 32) { sacc[wave][2 * lc] = a0; sacc[wave][2 * lc + 1] = a1; }
    __syncthreads();

    if (WITH_MID) {
        if (h == 0 && lane < 32) {
            float s0 = sacc[wave][2 * lc]     + sacc[wave + 1][2 * lc];
            float s1 = sacc[wave][2 * lc + 1] + sacc[wave + 1][2 * lc + 1];
            float dr = d_row[i];
            float dc = d_col[i];
            float m0 = fmaf(s0, dr, c1[2 * lc]);
            float m1 = fmaf(s1, dr, c1[2 * lc + 1]);
            *reinterpret_cast<float2*>(O1 + (size_t)i * 64 + 2 * lc) =
                make_float2(m0, m1);
            *reinterpret_cast<float2*>(O2 + (size_t)i * 64 + 2 * lc) =
                make_float2(dc * fmaxf(m0, 0.f), dc * fmaxf(m1, 0.f));
        }
    } else {
        if (h == 0 && lane < 32) {
            float dr = d_row[i];
            float s0 = (sacc[wave][2 * lc]     + sacc[wave + 1][2 * lc])     * dr;
            float s1 = (sacc[wave][2 * lc + 1] + sacc[wave + 1][2 * lc + 1]) * dr;
            sacc[wave][2 * lc]     = s0;
            sacc[wave][2 * lc + 1] = s1;
        }
        __syncthreads();
        const int rb2 = t >> 7;
        const int j = t & 127;
        const float* __restrict__ srow = sacc[2 * rb2];
        float acc = 0.f;
        #pragma unroll 8
        for (int k = 0; k < 64; ++k)
            acc = fmaf(srow[k], gc3[k * 128 + j], acc);
        int orow = blockIdx.x * 2 + rb2;
        O1[(size_t)orow * 128 + j] = fmaf(acc, s2g[j], t2g[j]);
    }
}

// ---------------------------------------------------------------------------
extern "C" void kernel_launch(void* const* d_in, const int* in_sizes, int n_in,
                              void* d_out, int out_size, void* d_ws, size_t ws_size,
                              hipStream_t stream) {
    const float* adj    = (const float*)d_in[0];
    const float* xdeg   = (const float*)d_in[1];
    const float* ydeg   = (const float*)d_in[2];
    const float* mlp_w1 = (const float*)d_in[3];
    const float* mlp_b1 = (const float*)d_in[4];
    const float* mlp_w2 = (const float*)d_in[5];
    const float* mlp_b2 = (const float*)d_in[6];
    const float* pe_w   = (const float*)d_in[7];
    const float* pe_b   = (const float*)d_in[8];
    const float* gc1_w  = (const float*)d_in[9];
    const float* lin2_w = (const float*)d_in[10];
    const float* lin2_b = (const float*)d_in[11];
    const float* gc3_w  = (const float*)d_in[12];
    const float* bn1_g  = (const float*)d_in[13];
    const float* bn1_b  = (const float*)d_in[14];
    const float* bn1_m  = (const float*)d_in[15];
    const float* bn1_v  = (const float*)d_in[16];
    const float* bn2_g  = (const float*)d_in[17];
    const float* bn2_b  = (const float*)d_in[18];
    const float* bn2_m  = (const float*)d_in[19];
    const float* bn2_v  = (const float*)d_in[20];

    float* out = (float*)d_out;                 // [NN * OUTW]
    float* mid = out + (size_t)NN * OUTW;       // [NN * MIDW]

    char* w = (char*)d_ws;
    float* a_vals = (float*)w;  w += (size_t)NN * CAP * 4;
    int*   a_cols = (int*)w;    w += (size_t)NN * CAP * 4;
    int*   cslot  = (int*)w;    w += (size_t)NN * SLOTCAP * 4;
    int*   cnt    = (int*)w;    w += (size_t)NN * NSTRIP * 4;
    int*   dflag  = (int*)w;    w += (size_t)NN * 4;
    float* rs_part= (float*)w;  w += (size_t)NN * NPAIR * 4;
    float* d_row  = (float*)w;  w += (size_t)NN * 4;
    float* d_col  = (float*)w;  w += (size_t)NN * 4;
    float* P      = (float*)w;  w += (size_t)CS_BLOCKS * NN * 4;
    float* W2     = (float*)w;  w += (size_t)INS * MIDW * 4;
    float* c1     = (float*)w;  w += 256;
    float* s2g    = (float*)w;  w += 512;
    float* t2g    = (float*)w;  w += 512;
    float* G      = (float*)w;  w += (size_t)NN * MIDW * 4;
    float* R      = (float*)w;  w += (size_t)NN * MIDW * 4;

    // K1: prep (block 0) + W2 GEMM (blocks 1..16, s1-folded) + count (17..)
    k_count_prep<<<1 + INS / 32 + NN * NSTRIP / 4, 256, 0, stream>>>(
        adj, cslot, cnt, dflag, gc1_w, lin2_w, lin2_b,
        bn1_g, bn1_b, bn1_m, bn1_v, bn2_g, bn2_b, bn2_m, bn2_v,
        W2, c1, s2g, t2g);
    // K2: Graw GEMM (blocks 0..127) + gather-fill (blocks 128..)
    k_fill_g<<<NN / 32 + NN * NPAIR / 4, 256, 0, stream>>>(
        xdeg, ydeg, cslot, cnt, dflag, mlp_w1, mlp_b1, mlp_w2, mlp_b2,
        a_vals, a_cols, rs_part, pe_w, pe_b, W2, G);
    // K3: colsum partials (wave-parallel)
    k_colsum<<<CS_BLOCKS, 256, 0, stream>>>(a_vals, a_cols, cnt, P);
    // K4: degree scales
    k_scale<<<NN / 512, 512, 0, stream>>>(rs_part, P, d_row, d_col);
    // K5: mid = Dr·(Â@(Dc·Graw)) + c1 ; R = d_col ⊙ relu(mid)
    k_spmm<true><<<NN / 2, 256, 0, stream>>>(
        a_vals, a_cols, cnt, G, d_row, d_col, c1,
        nullptr, nullptr, nullptr, mid, R);
    // K6: out = BN2((Dr·(Â@R)) @ gc3)
    k_spmm<false><<<NN / 2, 256, 0, stream>>>(
        a_vals, a_cols, cnt, R, d_row, d_col, nullptr,
        gc3_w, s2g, t2g, out, nullptr);
}

// Round 24
// 119.248 us; speedup vs baseline: 1.1052x; 1.1052x over previous
//
#include <hip/hip_runtime.h>
#include <hip/hip_bf16.h>

#define NN 4096
#define INS 512
#define HIDW 512
#define MIDW 64
#define OUTW 128
#define CAP 384   // per-row packed nonzero capacity (mean ~205)
#define SEG 96    // per-512-col-strip slot capacity
#define BN_EPS 1e-5f
#define NSTRIP 8                   // 512-col strips per row
#define NPAIR (NSTRIP / 2)         // 4 strip-pairs per row
#define SLOTCAP (NSTRIP * SEG)     // 768 slotted entries per row
#define CS_BLOCKS 256              // colsum blocks (16 rows each, 4/wave)
#define CS_ROWS 16
#define AUX_LDS 25600              // dynamic union: GEMM As+Bs / colsum ls

// ---------------------------------------------------------------------------
// device: thin GEMM block  C[32 rows x 64] = (A(+abias)) @ B[K x 64]
// Register-batched staging (all 24 loads in flight before LDS stores).
// ---------------------------------------------------------------------------
__device__ __forceinline__ void thin_block(
    const float* __restrict__ A, const float* __restrict__ B,
    const float* __restrict__ abias, float* __restrict__ C, int K, int bb,
    float (*As)[36], float (*Bs)[64])
{
    const int t = threadIdx.x;
    const int bm = bb * 32;
    const int c2 = t & 31, rg = t >> 5;

    float acc[4][2] = {};
    for (int k0 = 0; k0 < K; k0 += 64) {
        float va[8];
        #pragma unroll
        for (int l = 0; l < 8; ++l) {
            int e = t + l * 256;
            va[l] = A[(size_t)(bm + (e >> 6)) * K + k0 + (e & 63)];
        }
        float vb[16];
        #pragma unroll
        for (int l = 0; l < 16; ++l) {
            int e = t + l * 256;
            vb[l] = B[(size_t)(k0 + (e >> 6)) * 64 + (e & 63)];
        }
        #pragma unroll
        for (int l = 0; l < 8; ++l) {
            int e = t + l * 256;
            float v = va[l];
            if (abias) v += abias[k0 + (e & 63)];
            As[e & 63][e >> 6] = v;
        }
        #pragma unroll
        for (int l = 0; l < 16; ++l) {
            int e = t + l * 256;
            Bs[e >> 6][e & 63] = vb[l];
        }
        __syncthreads();
        #pragma unroll
        for (int k = 0; k < 64; ++k) {
            float4 a4 = *reinterpret_cast<const float4*>(&As[k][rg * 4]);
            float2 b2 = *reinterpret_cast<const float2*>(&Bs[k][2 * c2]);
            acc[0][0] = fmaf(a4.x, b2.x, acc[0][0]);
            acc[0][1] = fmaf(a4.x, b2.y, acc[0][1]);
            acc[1][0] = fmaf(a4.y, b2.x, acc[1][0]);
            acc[1][1] = fmaf(a4.y, b2.y, acc[1][1]);
            acc[2][0] = fmaf(a4.z, b2.x, acc[2][0]);
            acc[2][1] = fmaf(a4.z, b2.y, acc[2][1]);
            acc[3][0] = fmaf(a4.w, b2.x, acc[3][0]);
            acc[3][1] = fmaf(a4.w, b2.y, acc[3][1]);
        }
        __syncthreads();
    }
    #pragma unroll
    for (int u = 0; u < 4; ++u) {
        int r = bm + rg * 4 + u;
        *reinterpret_cast<float2*>(&C[(size_t)r * 64 + 2 * c2]) =
            make_float2(acc[u][0], acc[u][1]);
    }
}

// ---------------------------------------------------------------------------
// K1: block 0 = BN-fold prep (Wp, c1, s2g, t2g); blocks 1.. = adj count.
// ---------------------------------------------------------------------------
__global__ __launch_bounds__(256) void k_count_prep(
    const float* __restrict__ adj,
    int* __restrict__ cslot, int* __restrict__ cnt, int* __restrict__ dflag,
    const float* __restrict__ lin2_w, const float* __restrict__ lin2_b,
    const float* __restrict__ bn1_g, const float* __restrict__ bn1_b,
    const float* __restrict__ bn1_m, const float* __restrict__ bn1_v,
    const float* __restrict__ bn2_g, const float* __restrict__ bn2_b,
    const float* __restrict__ bn2_m, const float* __restrict__ bn2_v,
    float* __restrict__ Wp, float* __restrict__ c1,
    float* __restrict__ s2g, float* __restrict__ t2g)
{
    const int t = threadIdx.x;
    if (blockIdx.x == 0) {
        __shared__ float t1s[HIDW];
        for (int h = t; h < HIDW; h += 256) {
            float s1 = bn1_g[h] * rsqrtf(bn1_v[h] + BN_EPS);
            t1s[h] = bn1_b[h] - bn1_m[h] * s1;
            for (int m = 0; m < MIDW; ++m)
                Wp[(size_t)h * MIDW + m] = s1 * lin2_w[(size_t)h * MIDW + m];
        }
        __syncthreads();
        if (t < MIDW) {
            float acc = lin2_b[t];
            for (int h = 0; h < HIDW; ++h)
                acc = fmaf(t1s[h], lin2_w[(size_t)h * MIDW + t], acc);
            c1[t] = acc;
        } else if (t >= 64 && t < 64 + OUTW) {
            int j = t - 64;
            float s2 = bn2_g[j] * rsqrtf(bn2_v[j] + BN_EPS);
            s2g[j] = s2;
            t2g[j] = bn2_b[j] - bn2_m[j] * s2;
        }
        return;
    }
    const int wave = t >> 6, lane = t & 63;
    const int gw = (blockIdx.x - 1) * 4 + wave;
    const int i = gw >> 3, s = gw & 7;
    const int colbase = s * 512;
    const float* __restrict__ base = adj + (size_t)i * NN + colbase + 4 * lane;
    float4 a4a = *reinterpret_cast<const float4*>(base);
    float4 a4b = *reinterpret_cast<const float4*>(base + 256);
    const float av[8] = {a4a.x, a4a.y, a4a.z, a4a.w,
                         a4b.x, a4b.y, a4b.z, a4b.w};
    int* __restrict__ slot = cslot + (size_t)i * SLOTCAP + s * SEG;
    const unsigned long long lt = (1ULL << lane) - 1ULL;
    int run = 0;
    #pragma unroll
    for (int c = 0; c < 8; ++c) {
        int col = colbase + ((c < 4) ? (4 * lane + c) : (256 + 4 * lane + c - 4));
        bool diag = (col == i);
        bool act = (av[c] != 0.f) || diag;
        if (diag) dflag[i] = (av[c] != 0.f) ? 1 : 0;
        unsigned long long m = __ballot(act);
        if (act) {
            int pos = run + __popcll(m & lt);
            if (pos < SEG) slot[pos] = col;
        }
        run += __popcll(m);
    }
    if (lane == 0) cnt[gw] = (run < SEG) ? run : SEG;
}

// ---------------------------------------------------------------------------
// K2: blocks 0..15 = W2 = gc1 @ Wp ; blocks 16.. = gather-fill (strip-pairs)
// ---------------------------------------------------------------------------
__global__ __launch_bounds__(256) void k_fill_w2(
    const float* __restrict__ xdeg, const float* __restrict__ ydeg,
    const int* __restrict__ cslot, const int* __restrict__ cnt,
    const int* __restrict__ dflag,
    const float* __restrict__ w1, const float* __restrict__ b1,
    const float* __restrict__ w2, const float* __restrict__ b2,
    float* __restrict__ a_vals, int* __restrict__ a_cols,
    float* __restrict__ rs_part,
    const float* __restrict__ gc1_w, const float* __restrict__ Wp,
    float* __restrict__ W2)
{
    __shared__ float As[64][36];
    __shared__ float Bs[64][64];
    if (blockIdx.x < INS / 32) {
        thin_block(gc1_w, Wp, nullptr, W2, HIDW, blockIdx.x, As, Bs);
        return;
    }
    __shared__ float shb[16], sw1x[16], sw1y[16], sw2[32], sb2[2];
    const int t = threadIdx.x;
    const int wave = t >> 6, lane = t & 63;
    if (t < 16) {
        shb[t]  = b1[t] + w1[t];
        sw1x[t] = w1[16 + t];
        sw1y[t] = w1[32 + t];
    }
    if (t < 32) sw2[t] = w2[t];
    if (t < 2)  sb2[t] = b2[t];
    __syncthreads();

    const int q = __builtin_amdgcn_readfirstlane(
        (blockIdx.x - INS / 32) * 4 + wave);
    const int i = q >> 2;
    const int sp = (q & 3) * 2;
    const int* __restrict__ cb = cnt + i * NSTRIP;
    int wb = 0;
    #pragma unroll
    for (int ss = 0; ss < NSTRIP; ++ss) if (ss < sp) wb += cb[ss];
    const int n0 = cb[sp];
    const int ntot = n0 + cb[sp + 1];
    const int hasde = dflag[i];
    const int* __restrict__ slot = cslot + (size_t)i * SLOTCAP + sp * SEG;
    const float* __restrict__ xrow = xdeg + (size_t)i * NN;
    const float* __restrict__ yrow = ydeg + (size_t)i * NN;
    float* __restrict__ gv = a_vals + (size_t)i * CAP;
    int*   __restrict__ gc = a_cols + (size_t)i * CAP;

    float local = 0.f;
    for (int p = lane; p < ntot; p += 64) {
        int col = (p < n0) ? slot[p] : slot[SEG + p - n0];
        float x = xrow[col];
        float y = yrow[col];
        float l0 = sb2[0], l1 = sb2[1];
        #pragma unroll
        for (int w = 0; w < 16; ++w) {
            float hw = fmaf(x, sw1x[w], shb[w]);
            hw = fmaf(y, sw1y[w], hw);
            hw = fmaxf(hw, 0.f);
            l0 = fmaf(hw, sw2[2 * w],     l0);
            l1 = fmaf(hw, sw2[2 * w + 1], l1);
        }
        float v = 1.f / (1.f + __expf(l0 - l1));
        if (col == i) v = hasde ? (v + 1.f) : 1.f;
        int gp = wb + p;
        if (gp < CAP) { gc[gp] = col; gv[gp] = v; }
        local += v;
    }
    #pragma unroll
    for (int o = 32; o >= 1; o >>= 1)
        local += __shfl_down(local, o, 64);
    if (lane == 0) rs_part[q] = local;
}

// ---------------------------------------------------------------------------
// K3: fused aux (dynamic-LDS union, both roles ~60 VGPR):
// blocks 0..127  = Graw = (pe + pe_b) @ W2
// blocks 128..383 = wave-parallel colsum (16 rows, 4/wave, float4/int4)
// ---------------------------------------------------------------------------
__global__ __launch_bounds__(256) void k_aux(
    const float* __restrict__ pe_w, const float* __restrict__ pe_b,
    const float* __restrict__ W2, float* __restrict__ G,
    const float* __restrict__ a_vals, const int* __restrict__ a_cols,
    const int* __restrict__ cnt, float* __restrict__ P)
{
    extern __shared__ char smem[];
    if (blockIdx.x < NN / 32) {
        float (*As)[36] = reinterpret_cast<float (*)[36]>(smem);
        float (*Bs)[64] = reinterpret_cast<float (*)[64]>(smem + 9216);
        thin_block(pe_w, pe_b ? W2 : W2, pe_b, G, INS, blockIdx.x, As, Bs);
        return;
    }
    float* ls = reinterpret_cast<float*>(smem);   // 16 KB of the 25.6 KB
    const int t = threadIdx.x;
    const int wave = t >> 6, lane = t & 63;
    const int b = blockIdx.x - NN / 32;
    for (int j = t; j < NN; j += 256) ls[j] = 0.f;
    __syncthreads();
    const int r0 = b * CS_ROWS;
    #pragma unroll
    for (int rr = 0; rr < 4; ++rr) {
        const int r = r0 + wave * 4 + rr;
        int n = 0;
        #pragma unroll
        for (int ss = 0; ss < NSTRIP; ++ss) n += cnt[r * NSTRIP + ss];
        n = (n < CAP) ? n : CAP;
        const float* __restrict__ vr = a_vals + (size_t)r * CAP;
        const int*   __restrict__ cr = a_cols + (size_t)r * CAP;
        for (int p0 = 4 * lane; p0 < n; p0 += 256) {
            float4 v4 = *reinterpret_cast<const float4*>(vr + p0);
            int4   c4 = *reinterpret_cast<const int4*>(cr + p0);
            if (p0 + 0 < n) atomicAdd(&ls[c4.x], v4.x);
            if (p0 + 1 < n) atomicAdd(&ls[c4.y], v4.y);
            if (p0 + 2 < n) atomicAdd(&ls[c4.z], v4.z);
            if (p0 + 3 < n) atomicAdd(&ls[c4.w], v4.w);
        }
    }
    __syncthreads();
    for (int j = t; j < NN; j += 256)
        P[(size_t)b * NN + j] = ls[j];
}

// ---------------------------------------------------------------------------
// K4: degree scale factors
// ---------------------------------------------------------------------------
__global__ __launch_bounds__(512) void k_scale(
    const float* __restrict__ rs_part, const float* __restrict__ P,
    float* __restrict__ d_row, float* __restrict__ d_col)
{
    int j = blockIdx.x * 512 + threadIdx.x;
    float r = 0.f;
    #pragma unroll
    for (int s = 0; s < NPAIR; ++s) r += rs_part[j * NPAIR + s];
    d_row[j] = (r > 0.f) ? 1.f / sqrtf(r) : 0.f;
    float c = 0.f;
    for (int b = 0; b < CS_BLOCKS; ++b)
        c += P[(size_t)b * NN + j];
    d_col[j] = (c > 0.f) ? 1.f / sqrtf(c) : 0.f;
}

// ---------------------------------------------------------------------------
// K5/K6: 64-wide SpMM, two waves per row, 2 rows/block.
// COLFOLD: stage sv = a * d_col[col] (consumes Graw directly).
// WITH_MID: writes mid+R. !WITH_MID: fused epilogue out = (S@gc3)*s2 + t2.
// ---------------------------------------------------------------------------
template <bool WITH_MID>
__global__ __launch_bounds__(256) void k_spmm(
    const float* __restrict__ a_vals, const int* __restrict__ a_cols,
    const int* __restrict__ cnt, const float* __restrict__ X,
    const float* __restrict__ d_row, const float* __restrict__ d_col,
    const float* __restrict__ c1,
    const float* __restrict__ gc3, const float* __restrict__ s2g,
    const float* __restrict__ t2g,
    float* __restrict__ O1, float* __restrict__ O2)
{
    __shared__ float sv[2][CAP];
    __shared__ int   scl[2][CAP];
    __shared__ float sacc[4][64];
    const int t = threadIdx.x;
    const int wave = t >> 6, lane = t & 63;
    const int rb = wave >> 1, h = wave & 1;
    const int i = blockIdx.x * 2 + rb;
    int n = 0;
    #pragma unroll
    for (int ss = 0; ss < NSTRIP; ++ss) n += cnt[i * NSTRIP + ss];
    n = (n < CAP) ? n : CAP;
    const int n16 = (n + 15) & ~15;
    const float* __restrict__ vrow = a_vals + (size_t)i * CAP;
    const int*   __restrict__ crow = a_cols + (size_t)i * CAP;

    for (int p = h * 64 + lane; p < n16; p += 128) {
        bool ok = p < n;
        int c = ok ? crow[p] : 0;
        float v = ok ? vrow[p] : 0.f;
        if (WITH_MID) v *= d_col[c];       // fold Dc into the edge weight
        sv[rb][p]  = v;
        scl[rb][p] = c;
    }
    __syncthreads();

    const int eh = lane >> 5;
    const int lc = lane & 31;
    const int Q  = n16 >> 1;
    const int Qh = Q >> 1;

    float a0 = 0.f, a1 = 0.f;
    for (int q = h * Qh; q < (h + 1) * Qh; q += 4) {
        #pragma unroll
        for (int j = 0; j < 4; ++j) {
            int p = 2 * (q + j) + eh;
            float v = sv[rb][p];
            int c = scl[rb][p];
            float2 x = *reinterpret_cast<const float2*>(X + (size_t)c * 64 + 2 * lc);
            a0 = fmaf(v, x.x, a0);
            a1 = fmaf(v, x.y, a1);
        }
    }
    a0 += __shfl_xor(a0, 32);
    a1 += __shfl_xor(a1, 32);
    if (lane < 32) { sacc[wave][2 * lc] = a0; sacc[wave][2 * lc + 1] = a1; }
    __syncthreads();

    if (WITH_MID) {
        if (h == 0 && lane < 32) {
            float s0 = sacc[wave][2 * lc]     + sacc[wave + 1][2 * lc];
            float s1 = sacc[wave][2 * lc + 1] + sacc[wave + 1][2 * lc + 1];
            float dr = d_row[i];
            float dc = d_col[i];
            float m0 = fmaf(s0, dr, c1[2 * lc]);
            float m1 = fmaf(s1, dr, c1[2 * lc + 1]);
            *reinterpret_cast<float2*>(O1 + (size_t)i * 64 + 2 * lc) =
                make_float2(m0, m1);
            *reinterpret_cast<float2*>(O2 + (size_t)i * 64 + 2 * lc) =
                make_float2(dc * fmaxf(m0, 0.f), dc * fmaxf(m1, 0.f));
        }
    } else {
        if (h == 0 && lane < 32) {
            float dr = d_row[i];
            float s0 = (sacc[wave][2 * lc]     + sacc[wave + 1][2 * lc])     * dr;
            float s1 = (sacc[wave][2 * lc + 1] + sacc[wave + 1][2 * lc + 1]) * dr;
            sacc[wave][2 * lc]     = s0;
            sacc[wave][2 * lc + 1] = s1;
        }
        __syncthreads();
        const int rb2 = t >> 7;
        const int j = t & 127;
        const float* __restrict__ srow = sacc[2 * rb2];
        float acc = 0.f;
        #pragma unroll 8
        for (int k = 0; k < 64; ++k)
            acc = fmaf(srow[k], gc3[k * 128 + j], acc);
        int orow = blockIdx.x * 2 + rb2;
        O1[(size_t)orow * 128 + j] = fmaf(acc, s2g[j], t2g[j]);
    }
}

// ---------------------------------------------------------------------------
extern "C" void kernel_launch(void* const* d_in, const int* in_sizes, int n_in,
                              void* d_out, int out_size, void* d_ws, size_t ws_size,
                              hipStream_t stream) {
    const float* adj    = (const float*)d_in[0];
    const float* xdeg   = (const float*)d_in[1];
    const float* ydeg   = (const float*)d_in[2];
    const float* mlp_w1 = (const float*)d_in[3];
    const float* mlp_b1 = (const float*)d_in[4];
    const float* mlp_w2 = (const float*)d_in[5];
    const float* mlp_b2 = (const float*)d_in[6];
    const float* pe_w   = (const float*)d_in[7];
    const float* pe_b   = (const float*)d_in[8];
    const float* gc1_w  = (const float*)d_in[9];
    const float* lin2_w = (const float*)d_in[10];
    const float* lin2_b = (const float*)d_in[11];
    const float* gc3_w  = (const float*)d_in[12];
    const float* bn1_g  = (const float*)d_in[13];
    const float* bn1_b  = (const float*)d_in[14];
    const float* bn1_m  = (const float*)d_in[15];
    const float* bn1_v  = (const float*)d_in[16];
    const float* bn2_g  = (const float*)d_in[17];
    const float* bn2_b  = (const float*)d_in[18];
    const float* bn2_m  = (const float*)d_in[19];
    const float* bn2_v  = (const float*)d_in[20];

    float* out = (float*)d_out;                 // [NN * OUTW]
    float* mid = out + (size_t)NN * OUTW;       // [NN * MIDW]

    char* w = (char*)d_ws;
    float* a_vals = (float*)w;  w += (size_t)NN * CAP * 4;
    int*   a_cols = (int*)w;    w += (size_t)NN * CAP * 4;
    int*   cslot  = (int*)w;    w += (size_t)NN * SLOTCAP * 4;
    int*   cnt    = (int*)w;    w += (size_t)NN * NSTRIP * 4;
    int*   dflag  = (int*)w;    w += (size_t)NN * 4;
    float* rs_part= (float*)w;  w += (size_t)NN * NPAIR * 4;
    float* d_row  = (float*)w;  w += (size_t)NN * 4;
    float* d_col  = (float*)w;  w += (size_t)NN * 4;
    float* P      = (float*)w;  w += (size_t)CS_BLOCKS * NN * 4;
    float* Wp     = (float*)w;  w += (size_t)HIDW * MIDW * 4;
    float* W2     = (float*)w;  w += (size_t)INS * MIDW * 4;
    float* c1     = (float*)w;  w += 256;
    float* s2g    = (float*)w;  w += 512;
    float* t2g    = (float*)w;  w += 512;
    float* G      = (float*)w;  w += (size_t)NN * MIDW * 4;
    float* R      = (float*)w;  w += (size_t)NN * MIDW * 4;

    // K1: BN-prep (block 0) + adj count (blocks 1..8192)
    k_count_prep<<<NN * NSTRIP / 4 + 1, 256, 0, stream>>>(
        adj, cslot, cnt, dflag, lin2_w, lin2_b, bn1_g, bn1_b, bn1_m, bn1_v,
        bn2_g, bn2_b, bn2_m, bn2_v, Wp, c1, s2g, t2g);
    // K2: W2 GEMM (blocks 0..15) + gather-fill (blocks 16..)
    k_fill_w2<<<INS / 32 + NN * NPAIR / 4, 256, 0, stream>>>(
        xdeg, ydeg, cslot, cnt, dflag, mlp_w1, mlp_b1, mlp_w2, mlp_b2,
        a_vals, a_cols, rs_part, gc1_w, Wp, W2);
    // K3: fused Graw GEMM (blocks 0..127) + colsum (blocks 128..383)
    k_aux<<<NN / 32 + CS_BLOCKS, 256, AUX_LDS, stream>>>(
        pe_w, pe_b, W2, G, a_vals, a_cols, cnt, P);
    // K4: degree scales
    k_scale<<<NN / 512, 512, 0, stream>>>(rs_part, P, d_row, d_col);
    // K5: mid = Dr·(Â@(Dc·Graw)) + c1 ; R = d_col ⊙ relu(mid)
    k_spmm<true><<<NN / 2, 256, 0, stream>>>(
        a_vals, a_cols, cnt, G, d_row, d_col, c1,
        nullptr, nullptr, nullptr, mid, R);
    // K6: out = BN2((Dr·(Â@R)) @ gc3)
    k_spmm<false><<<NN / 2, 256, 0, stream>>>(
        a_vals, a_cols, cnt, R, d_row, d_col, nullptr,
        gc3_w, s2g, t2g, out, nullptr);
}